// Round 1
// baseline (857.515 us; speedup 1.0000x reference)
//
#include <hip/hip_runtime.h>
#include <hip/hip_bf16.h>

#define N_NODES 100000
#define N_EDGES 1600000
#define IN_DIM 128
#define C1 256      // HEADS*HID = 4*64
#define HID 64
#define HEADS 4
#define OUT_DIM 32
#define SLOPE 0.2f

__device__ __forceinline__ float leaky(float t) { return t > 0.f ? t : SLOPE * t; }

// ---------------- CSR build ----------------
__global__ void k_hist(const int* __restrict__ dst, int* __restrict__ cnt, int e) {
    int i = blockIdx.x * 256 + threadIdx.x;
    if (i < e) atomicAdd(&cnt[dst[i]], 1);
}

__global__ void k_scan_local(const int* __restrict__ cnt, int* __restrict__ row_ptr,
                             int* __restrict__ bs, int n) {
    __shared__ int sm[256];
    int tid = threadIdx.x;
    int gid = blockIdx.x * 256 + tid;
    int v = (gid < n) ? cnt[gid] : 0;
    sm[tid] = v;
    __syncthreads();
    for (int off = 1; off < 256; off <<= 1) {
        int u = (tid >= off) ? sm[tid - off] : 0;
        __syncthreads();
        sm[tid] += u;
        __syncthreads();
    }
    if (gid < n) row_ptr[gid] = sm[tid] - v;   // block-local exclusive
    if (tid == 255) bs[blockIdx.x] = sm[255];
}

__global__ void k_scan_totals(int* __restrict__ bs, int nb, int* __restrict__ row_ptr_last) {
    __shared__ int sm[512];
    int t = threadIdx.x;
    int v = (t < nb) ? bs[t] : 0;
    sm[t] = v;
    __syncthreads();
    for (int off = 1; off < 512; off <<= 1) {
        int u = (t >= off) ? sm[t - off] : 0;
        __syncthreads();
        sm[t] += u;
        __syncthreads();
    }
    if (t == nb - 1) *row_ptr_last = sm[t];       // total edge count
    if (t < nb) bs[t] = (t == 0) ? 0 : sm[t - 1]; // exclusive block offsets
}

__global__ void k_scan_add(int* __restrict__ row_ptr, int* __restrict__ offs,
                           const int* __restrict__ bs, int n) {
    int gid = blockIdx.x * 256 + threadIdx.x;
    if (gid < n) {
        int v = row_ptr[gid] + bs[blockIdx.x];
        row_ptr[gid] = v;
        offs[gid] = v;
    }
}

__global__ void k_scatter(const int* __restrict__ src, const int* __restrict__ dst,
                          int* __restrict__ offs, int* __restrict__ col, int e) {
    int i = blockIdx.x * 256 + threadIdx.x;
    if (i < e) {
        int p = atomicAdd(&offs[dst[i]], 1);
        col[p] = src[i];
    }
}

// ---------------- GEMM1: h1 = x @ W1  (N x 128) @ (128 x 256) ----------------
#define BM1 64
__launch_bounds__(256)
__global__ void k_gemm1(const float* __restrict__ x, const float* __restrict__ W,
                        float* __restrict__ h1, int n) {
    __shared__ float sA[BM1 * IN_DIM];  // 32 KB
    int tid = threadIdx.x;
    int row0 = blockIdx.x * BM1;
    for (int i = tid; i < BM1 * IN_DIM; i += 256) {
        int r = i >> 7, k = i & 127;
        int gr = row0 + r;
        sA[i] = (gr < n) ? x[gr * IN_DIM + k] : 0.f;
    }
    __syncthreads();
    float acc[BM1];
#pragma unroll
    for (int r = 0; r < BM1; r++) acc[r] = 0.f;
    for (int kk = 0; kk < IN_DIM; kk += 8) {
        float wreg[8];
#pragma unroll
        for (int i = 0; i < 8; i++) wreg[i] = W[(kk + i) * C1 + tid];
#pragma unroll
        for (int r = 0; r < BM1; r++) {
#pragma unroll
            for (int i = 0; i < 8; i++) acc[r] += sA[r * IN_DIM + kk + i] * wreg[i];
        }
    }
    for (int r = 0; r < BM1; r++) {
        int gr = row0 + r;
        if (gr < n) h1[gr * C1 + tid] = acc[r];
    }
}

// ---------------- att logits layer1: per node, 256 threads ----------------
__global__ void k_att1(const float* __restrict__ h1, const float* __restrict__ a_src,
                       const float* __restrict__ a_dst, float* __restrict__ es,
                       float* __restrict__ ed) {
    int nIdx = blockIdx.x;
    int tid = threadIdx.x;  // 256
    float v = h1[nIdx * C1 + tid];
    float ps = v * a_src[tid];
    float pd = v * a_dst[tid];
#pragma unroll
    for (int off = 32; off; off >>= 1) {
        ps += __shfl_xor(ps, off);
        pd += __shfl_xor(pd, off);
    }
    if ((tid & 63) == 0) {
        es[nIdx * HEADS + (tid >> 6)] = ps;
        ed[nIdx * HEADS + (tid >> 6)] = pd;
    }
}

// ---------------- layer1 aggregation: one wave per node ----------------
__global__ void k_aggr1(const float* __restrict__ h1, const float* __restrict__ es,
                        const float* __restrict__ ed, const int* __restrict__ row_ptr,
                        const int* __restrict__ col, const float* __restrict__ b,
                        float* __restrict__ out1, int n) {
    int lane = threadIdx.x & 63;
    int node = blockIdx.x * 4 + (threadIdx.x >> 6);
    if (node >= n) return;
    float edv[4], els[4], m[4];
#pragma unroll
    for (int k = 0; k < 4; k++) edv[k] = ed[node * 4 + k];
#pragma unroll
    for (int k = 0; k < 4; k++) {
        els[k] = leaky(es[node * 4 + k] + edv[k]);
        m[k] = els[k];
    }
    int beg = row_ptr[node], end = row_ptr[node + 1];
    // pass 1: max
    for (int base = beg; base < end; base += 64) {
        int j = base + lane;
        if (j < end) {
            int s = col[j];
#pragma unroll
            for (int k = 0; k < 4; k++) m[k] = fmaxf(m[k], leaky(es[s * 4 + k] + edv[k]));
        }
    }
#pragma unroll
    for (int off = 32; off; off >>= 1) {
#pragma unroll
        for (int k = 0; k < 4; k++) m[k] = fmaxf(m[k], __shfl_xor(m[k], off));
    }
    // pass 2: exp-sum + weighted gather
    float exs[4], dl[4], acc[4];
#pragma unroll
    for (int k = 0; k < 4; k++) {
        exs[k] = expf(els[k] - m[k]);
        dl[k] = (lane == 0) ? exs[k] : 0.f;
        acc[k] = exs[k] * h1[node * C1 + k * 64 + lane];
    }
    for (int base = beg; base < end; base += 64) {
        int nv = end - base;
        if (nv > 64) nv = 64;
        int j = base + lane;
        float exl[4] = {0.f, 0.f, 0.f, 0.f};
        int s = 0;
        if (j < end) {
            s = col[j];
#pragma unroll
            for (int k = 0; k < 4; k++) {
                float t = expf(leaky(es[s * 4 + k] + edv[k]) - m[k]);
                exl[k] = t;
                dl[k] += t;
            }
        }
        for (int j2 = 0; j2 < nv; j2++) {
            int sb = __shfl(s, j2);
            float e0 = __shfl(exl[0], j2);
            float e1 = __shfl(exl[1], j2);
            float e2 = __shfl(exl[2], j2);
            float e3 = __shfl(exl[3], j2);
            const float* hp = h1 + sb * C1 + lane;
            acc[0] += e0 * hp[0];
            acc[1] += e1 * hp[64];
            acc[2] += e2 * hp[128];
            acc[3] += e3 * hp[192];
        }
    }
#pragma unroll
    for (int off = 32; off; off >>= 1) {
#pragma unroll
        for (int k = 0; k < 4; k++) dl[k] += __shfl_xor(dl[k], off);
    }
#pragma unroll
    for (int k = 0; k < 4; k++) {
        float o = acc[k] / (dl[k] + 1e-16f) + b[k * 64 + lane];
        out1[node * C1 + k * 64 + lane] = o > 0.f ? o : expm1f(o);  // ELU fused
    }
}

// ---------------- GEMM2: h2 = out1 @ W2  (N x 256)@(256 x 32), fused e2 ----------------
__launch_bounds__(256)
__global__ void k_gemm2(const float* __restrict__ A, const float* __restrict__ W,
                        float* __restrict__ h2, const float* __restrict__ a_src,
                        const float* __restrict__ a_dst, float* __restrict__ es,
                        float* __restrict__ ed, int n) {
    __shared__ float sW[C1 * OUT_DIM];  // 32 KB
    __shared__ float sA[8 * C1];        // 8 KB
    int tid = threadIdx.x;
    for (int i = tid; i < C1 * OUT_DIM; i += 256) sW[i] = W[i];
    int row0 = blockIdx.x * 8;
    for (int i = tid; i < 8 * C1; i += 256) {
        int r = i >> 8, k = i & 255;
        int gr = row0 + r;
        sA[i] = (gr < n) ? A[gr * C1 + k] : 0.f;
    }
    __syncthreads();
    int col = tid & 31, r = tid >> 5;
    float acc = 0.f;
#pragma unroll 8
    for (int k = 0; k < C1; k++) acc += sA[r * C1 + k] * sW[k * OUT_DIM + col];
    float ps = acc * a_src[col], pd = acc * a_dst[col];
#pragma unroll
    for (int off = 16; off; off >>= 1) {
        ps += __shfl_xor(ps, off, 32);
        pd += __shfl_xor(pd, off, 32);
    }
    int gr = row0 + r;
    if (gr < n) {
        h2[gr * OUT_DIM + col] = acc;
        if (col == 0) {
            es[gr] = ps;
            ed[gr] = pd;
        }
    }
}

// ---------------- layer2 aggregation: one wave per node, 32 channels ----------------
__global__ void k_aggr2(const float* __restrict__ h2, const float* __restrict__ es,
                        const float* __restrict__ ed, const int* __restrict__ row_ptr,
                        const int* __restrict__ col, const float* __restrict__ b,
                        float* __restrict__ emb, int n) {
    int lane = threadIdx.x & 63;
    int node = blockIdx.x * 4 + (threadIdx.x >> 6);
    if (node >= n) return;
    float edv = ed[node];
    float els = leaky(es[node] + edv);
    int beg = row_ptr[node], end = row_ptr[node + 1];
    float m = els;
    for (int base = beg; base < end; base += 64) {
        int j = base + lane;
        if (j < end) {
            int s = col[j];
            m = fmaxf(m, leaky(es[s] + edv));
        }
    }
#pragma unroll
    for (int off = 32; off; off >>= 1) m = fmaxf(m, __shfl_xor(m, off));
    float exs = expf(els - m);
    float dl = (lane == 0) ? exs : 0.f;
    int c = lane & 31;
    float acc = (lane < 32) ? exs * h2[node * OUT_DIM + c] : 0.f;
    int half = lane >> 5;
    for (int base = beg; base < end; base += 64) {
        int nv = end - base;
        if (nv > 64) nv = 64;
        int j = base + lane;
        float exl = 0.f;
        int s = 0;
        if (j < end) {
            s = col[j];
            float t = expf(leaky(es[s] + edv) - m);
            exl = t;
            dl += t;
        }
        for (int j2 = 0; j2 < nv; j2 += 2) {
            int jj = j2 + half;
            int sb = __shfl(s, jj);
            float eb = __shfl(exl, jj);
            if (jj < nv) acc += eb * h2[sb * OUT_DIM + c];
        }
    }
    acc += __shfl_xor(acc, 32);
#pragma unroll
    for (int off = 32; off; off >>= 1) dl += __shfl_xor(dl, off);
    if (lane < 32) emb[node * OUT_DIM + c] = acc / (dl + 1e-16f) + b[c];
}

extern "C" void kernel_launch(void* const* d_in, const int* in_sizes, int n_in,
                              void* d_out, int out_size, void* d_ws, size_t ws_size,
                              hipStream_t stream) {
    const float* x = (const float*)d_in[0];
    const int* edge_index = (const int*)d_in[1];
    const float* W1 = (const float*)d_in[2];
    const float* a_src1 = (const float*)d_in[3];
    const float* a_dst1 = (const float*)d_in[4];
    const float* b1 = (const float*)d_in[5];
    const float* W2 = (const float*)d_in[6];
    const float* a_src2 = (const float*)d_in[7];
    const float* a_dst2 = (const float*)d_in[8];
    const float* b2 = (const float*)d_in[9];
    float* emb = (float*)d_out;

    const int* src = edge_index;
    const int* dst = edge_index + N_EDGES;

    // workspace carve
    char* w = (char*)d_ws;
    auto alloc = [&](size_t bytes) {
        char* p = w;
        w += (bytes + 255) & ~(size_t)255;
        return (void*)p;
    };
    const int NB = (N_NODES + 255) / 256;  // 391
    int* cnt = (int*)alloc(N_NODES * 4);
    int* row_ptr = (int*)alloc((N_NODES + 1) * 4);
    int* offs = (int*)alloc(N_NODES * 4);
    int* bs = (int*)alloc(NB * 4);
    int* col = (int*)alloc((size_t)N_EDGES * 4);
    float* h1 = (float*)alloc((size_t)N_NODES * C1 * 4);
    float* es1 = (float*)alloc(N_NODES * HEADS * 4);
    float* ed1 = (float*)alloc(N_NODES * HEADS * 4);
    float* out1 = (float*)alloc((size_t)N_NODES * C1 * 4);
    float* h2 = (float*)alloc((size_t)N_NODES * OUT_DIM * 4);
    float* es2 = (float*)alloc(N_NODES * 4);
    float* ed2 = (float*)alloc(N_NODES * 4);

    // CSR build
    hipMemsetAsync(cnt, 0, N_NODES * 4, stream);
    k_hist<<<(N_EDGES + 255) / 256, 256, 0, stream>>>(dst, cnt, N_EDGES);
    k_scan_local<<<NB, 256, 0, stream>>>(cnt, row_ptr, bs, N_NODES);
    k_scan_totals<<<1, 512, 0, stream>>>(bs, NB, row_ptr + N_NODES);
    k_scan_add<<<NB, 256, 0, stream>>>(row_ptr, offs, bs, N_NODES);
    k_scatter<<<(N_EDGES + 255) / 256, 256, 0, stream>>>(src, dst, offs, col, N_EDGES);

    // layer 1
    k_gemm1<<<(N_NODES + BM1 - 1) / BM1, 256, 0, stream>>>(x, W1, h1, N_NODES);
    k_att1<<<N_NODES, 256, 0, stream>>>(h1, a_src1, a_dst1, es1, ed1);
    k_aggr1<<<(N_NODES + 3) / 4, 256, 0, stream>>>(h1, es1, ed1, row_ptr, col, b1, out1, N_NODES);

    // layer 2
    k_gemm2<<<(N_NODES + 7) / 8, 256, 0, stream>>>(out1, W2, h2, a_src2, a_dst2, es2, ed2, N_NODES);
    k_aggr2<<<(N_NODES + 3) / 4, 256, 0, stream>>>(h2, es2, ed2, row_ptr, col, b2, emb, N_NODES);
}

// Round 2
// 740.261 us; speedup vs baseline: 1.1584x; 1.1584x over previous
//
#include <hip/hip_runtime.h>
#include <hip/hip_bf16.h>
#include <hip/hip_fp16.h>

#define N_NODES 100000
#define N_EDGES 1600000
#define IN_DIM 128
#define C1 256      // HEADS*HID = 4*64
#define HID 64
#define HEADS 4
#define OUT_DIM 32
#define SLOPE 0.2f

__device__ __forceinline__ float leaky(float t) { return t > 0.f ? t : SLOPE * t; }

// ---------------- CSR build ----------------
__global__ void k_hist(const int* __restrict__ dst, int* __restrict__ cnt, int e) {
    int i = blockIdx.x * 256 + threadIdx.x;
    if (i < e) atomicAdd(&cnt[dst[i]], 1);
}

__global__ void k_scan_local(const int* __restrict__ cnt, int* __restrict__ row_ptr,
                             int* __restrict__ bs, int n) {
    __shared__ int sm[256];
    int tid = threadIdx.x;
    int gid = blockIdx.x * 256 + tid;
    int v = (gid < n) ? cnt[gid] : 0;
    sm[tid] = v;
    __syncthreads();
    for (int off = 1; off < 256; off <<= 1) {
        int u = (tid >= off) ? sm[tid - off] : 0;
        __syncthreads();
        sm[tid] += u;
        __syncthreads();
    }
    if (gid < n) row_ptr[gid] = sm[tid] - v;   // block-local exclusive
    if (tid == 255) bs[blockIdx.x] = sm[255];
}

__global__ void k_scan_totals(int* __restrict__ bs, int nb, int* __restrict__ row_ptr_last) {
    __shared__ int sm[512];
    int t = threadIdx.x;
    int v = (t < nb) ? bs[t] : 0;
    sm[t] = v;
    __syncthreads();
    for (int off = 1; off < 512; off <<= 1) {
        int u = (t >= off) ? sm[t - off] : 0;
        __syncthreads();
        sm[t] += u;
        __syncthreads();
    }
    if (t == nb - 1) *row_ptr_last = sm[t];       // total edge count
    if (t < nb) bs[t] = (t == 0) ? 0 : sm[t - 1]; // exclusive block offsets
}

__global__ void k_scan_add(int* __restrict__ row_ptr, int* __restrict__ offs,
                           const int* __restrict__ bs, int n) {
    int gid = blockIdx.x * 256 + threadIdx.x;
    if (gid < n) {
        int v = row_ptr[gid] + bs[blockIdx.x];
        row_ptr[gid] = v;
        offs[gid] = v;
    }
}

__global__ void k_scatter(const int* __restrict__ src, const int* __restrict__ dst,
                          int* __restrict__ offs, int* __restrict__ col, int e) {
    int i = blockIdx.x * 256 + threadIdx.x;
    if (i < e) {
        int p = atomicAdd(&offs[dst[i]], 1);
        col[p] = src[i];
    }
}

// ---------------- GEMM1: h1 = x @ W1  (N x 128) @ (128 x 256), fp16 out ----------------
// h1h layout: [node][channel(64)][head(4)]  -> per-lane uint2 gather in aggr1
#define BM1 64
__launch_bounds__(256)
__global__ void k_gemm1(const float* __restrict__ x, const float* __restrict__ W,
                        __half* __restrict__ h1h, int n) {
    __shared__ float sA[BM1 * IN_DIM];  // 32 KB
    int tid = threadIdx.x;
    int row0 = blockIdx.x * BM1;
    for (int i = tid; i < BM1 * IN_DIM; i += 256) {
        int r = i >> 7, k = i & 127;
        int gr = row0 + r;
        sA[i] = (gr < n) ? x[(size_t)gr * IN_DIM + k] : 0.f;
    }
    __syncthreads();
    float acc[BM1];
#pragma unroll
    for (int r = 0; r < BM1; r++) acc[r] = 0.f;
    for (int kk = 0; kk < IN_DIM; kk += 8) {
        float wreg[8];
#pragma unroll
        for (int i = 0; i < 8; i++) wreg[i] = W[(kk + i) * C1 + tid];
#pragma unroll
        for (int r = 0; r < BM1; r++) {
#pragma unroll
            for (int i = 0; i < 8; i++) acc[r] += sA[r * IN_DIM + kk + i] * wreg[i];
        }
    }
    // stage fp16 in LDS (reuse sA) in gather layout, then coalesced store
    __syncthreads();
    __half* sH = (__half*)sA;  // 64*256 halves = 32 KB
    int c = tid & 63, head = tid >> 6;
#pragma unroll
    for (int r = 0; r < BM1; r++) sH[r * 256 + c * 4 + head] = __float2half(acc[r]);
    __syncthreads();
    uint* gdst = (uint*)(h1h + (size_t)row0 * 256);
    const uint* gsrc = (const uint*)sH;
    for (int i = tid; i < BM1 * 128; i += 256) {
        if (row0 + (i >> 7) < n) gdst[i] = gsrc[i];
    }
}

// ---------------- att logits layer1: one wave per node ----------------
__global__ void k_att1(const __half* __restrict__ h1h, const float* __restrict__ a_src,
                       const float* __restrict__ a_dst, float* __restrict__ es,
                       float* __restrict__ ed, int n) {
    int lane = threadIdx.x & 63;
    int node = blockIdx.x * 4 + (threadIdx.x >> 6);
    if (node >= n) return;
    uint2 raw = *reinterpret_cast<const uint2*>(h1h + (size_t)node * 256 + lane * 4);
    __half2 p01 = *reinterpret_cast<__half2*>(&raw.x);
    __half2 p23 = *reinterpret_cast<__half2*>(&raw.y);
    float v[4] = {__half2float(p01.x), __half2float(p01.y),
                  __half2float(p23.x), __half2float(p23.y)};
    float ps[4], pd[4];
#pragma unroll
    for (int k = 0; k < 4; k++) {
        ps[k] = v[k] * a_src[k * 64 + lane];
        pd[k] = v[k] * a_dst[k * 64 + lane];
    }
#pragma unroll
    for (int off = 32; off; off >>= 1) {
#pragma unroll
        for (int k = 0; k < 4; k++) {
            ps[k] += __shfl_xor(ps[k], off);
            pd[k] += __shfl_xor(pd[k], off);
        }
    }
    if (lane == 0) {
        ((float4*)es)[node] = make_float4(ps[0], ps[1], ps[2], ps[3]);
        ((float4*)ed)[node] = make_float4(pd[0], pd[1], pd[2], pd[3]);
    }
}

// ---------------- layer1 aggregation: one wave per node, single pass ----------------
__global__ void k_aggr1(const __half* __restrict__ h1h, const float* __restrict__ es,
                        const float* __restrict__ ed, const int* __restrict__ row_ptr,
                        const int* __restrict__ col, const float* __restrict__ b,
                        __half* __restrict__ out1h, int n) {
    int lane = threadIdx.x & 63;
    int node = blockIdx.x * 4 + (threadIdx.x >> 6);
    if (node >= n) return;
    float4 edv4 = ((const float4*)ed)[node];
    float4 esv4 = ((const float4*)es)[node];
    float edv[4] = {edv4.x, edv4.y, edv4.z, edv4.w};
    float esv[4] = {esv4.x, esv4.y, esv4.z, esv4.w};
    // self contribution
    uint2 sraw = *reinterpret_cast<const uint2*>(h1h + (size_t)node * 256 + lane * 4);
    __half2 sp01 = *reinterpret_cast<__half2*>(&sraw.x);
    __half2 sp23 = *reinterpret_cast<__half2*>(&sraw.y);
    float sv[4] = {__half2float(sp01.x), __half2float(sp01.y),
                   __half2float(sp23.x), __half2float(sp23.y)};
    float dl[4], acc[4];
#pragma unroll
    for (int k = 0; k < 4; k++) {
        float t = expf(leaky(esv[k] + edv[k]));
        dl[k] = (lane == 0) ? t : 0.f;
        acc[k] = t * sv[k];
    }
    int beg = row_ptr[node], end = row_ptr[node + 1];
    for (int base = beg; base < end; base += 64) {
        int nv = end - base;
        if (nv > 64) nv = 64;
        int j = base + lane;
        int s = 0;
        float exl[4] = {0.f, 0.f, 0.f, 0.f};
        if (j < end) {
            s = col[j];
            float4 e4 = ((const float4*)es)[s];
            exl[0] = expf(leaky(e4.x + edv[0]));
            exl[1] = expf(leaky(e4.y + edv[1]));
            exl[2] = expf(leaky(e4.z + edv[2]));
            exl[3] = expf(leaky(e4.w + edv[3]));
            dl[0] += exl[0];
            dl[1] += exl[1];
            dl[2] += exl[2];
            dl[3] += exl[3];
        }
        for (int j2 = 0; j2 < nv; j2++) {
            int sb = __shfl(s, j2);
            float e0 = __shfl(exl[0], j2);
            float e1 = __shfl(exl[1], j2);
            float e2 = __shfl(exl[2], j2);
            float e3 = __shfl(exl[3], j2);
            uint2 raw = *reinterpret_cast<const uint2*>(h1h + (size_t)sb * 256 + lane * 4);
            __half2 p01 = *reinterpret_cast<__half2*>(&raw.x);
            __half2 p23 = *reinterpret_cast<__half2*>(&raw.y);
            acc[0] += e0 * __half2float(p01.x);
            acc[1] += e1 * __half2float(p01.y);
            acc[2] += e2 * __half2float(p23.x);
            acc[3] += e3 * __half2float(p23.y);
        }
    }
#pragma unroll
    for (int off = 32; off; off >>= 1) {
#pragma unroll
        for (int k = 0; k < 4; k++) dl[k] += __shfl_xor(dl[k], off);
    }
#pragma unroll
    for (int k = 0; k < 4; k++) {
        float o = acc[k] / (dl[k] + 1e-16f) + b[k * 64 + lane];
        o = o > 0.f ? o : expm1f(o);  // ELU fused
        out1h[(size_t)node * 256 + k * 64 + lane] = __float2half(o);
    }
}

// ---------------- GEMM2: h2 = out1 @ W2  (N x 256)@(256 x 32), fused e2, fp16 ----------------
__launch_bounds__(256)
__global__ void k_gemm2(const __half* __restrict__ A, const float* __restrict__ W,
                        __half* __restrict__ h2h, const float* __restrict__ a_src,
                        const float* __restrict__ a_dst, float* __restrict__ es,
                        float* __restrict__ ed, int n) {
    __shared__ float sW[C1 * OUT_DIM];  // 32 KB
    __shared__ float sA[8 * C1];        // 8 KB
    int tid = threadIdx.x;
    for (int i = tid; i < C1 * OUT_DIM; i += 256) sW[i] = W[i];
    int row0 = blockIdx.x * 8;
    for (int i = tid; i < 8 * C1; i += 256) {
        int r = i >> 8, k = i & 255;
        int gr = row0 + r;
        sA[i] = (gr < n) ? __half2float(A[(size_t)gr * C1 + k]) : 0.f;
    }
    __syncthreads();
    int col = tid & 31, r = tid >> 5;
    float acc = 0.f;
#pragma unroll 8
    for (int k = 0; k < C1; k++) acc += sA[r * C1 + k] * sW[k * OUT_DIM + col];
    float ps = acc * a_src[col], pd = acc * a_dst[col];
#pragma unroll
    for (int off = 16; off; off >>= 1) {
        ps += __shfl_xor(ps, off, 32);
        pd += __shfl_xor(pd, off, 32);
    }
    int gr = row0 + r;
    if (gr < n) {
        h2h[(size_t)gr * OUT_DIM + col] = __float2half(acc);
        if (col == 0) {
            es[gr] = ps;
            ed[gr] = pd;
        }
    }
}

// ---------------- layer2 aggregation: one wave per node, single pass ----------------
__global__ void k_aggr2(const __half* __restrict__ h2h, const float* __restrict__ es,
                        const float* __restrict__ ed, const int* __restrict__ row_ptr,
                        const int* __restrict__ col, const float* __restrict__ b,
                        float* __restrict__ emb, int n) {
    int lane = threadIdx.x & 63;
    int node = blockIdx.x * 4 + (threadIdx.x >> 6);
    if (node >= n) return;
    float edv = ed[node];
    float selft = expf(leaky(es[node] + edv));
    int c = lane & 31, half_ = lane >> 5;
    float acc = (lane < 32) ? selft * __half2float(h2h[(size_t)node * OUT_DIM + c]) : 0.f;
    float dl = (lane == 0) ? selft : 0.f;
    int beg = row_ptr[node], end = row_ptr[node + 1];
    for (int base = beg; base < end; base += 64) {
        int nv = end - base;
        if (nv > 64) nv = 64;
        int j = base + lane;
        int s = 0;
        float exl = 0.f;
        if (j < end) {
            s = col[j];
            exl = expf(leaky(es[s] + edv));
            dl += exl;
        }
        for (int j2 = 0; j2 < nv; j2 += 2) {
            int jj = j2 + half_;
            int sb = __shfl(s, jj);
            float eb = __shfl(exl, jj);
            if (jj < nv) acc += eb * __half2float(h2h[(size_t)sb * OUT_DIM + c]);
        }
    }
    acc += __shfl_xor(acc, 32);
#pragma unroll
    for (int off = 32; off; off >>= 1) dl += __shfl_xor(dl, off);
    if (lane < 32) emb[(size_t)node * OUT_DIM + c] = acc / (dl + 1e-16f) + b[c];
}

extern "C" void kernel_launch(void* const* d_in, const int* in_sizes, int n_in,
                              void* d_out, int out_size, void* d_ws, size_t ws_size,
                              hipStream_t stream) {
    const float* x = (const float*)d_in[0];
    const int* edge_index = (const int*)d_in[1];
    const float* W1 = (const float*)d_in[2];
    const float* a_src1 = (const float*)d_in[3];
    const float* a_dst1 = (const float*)d_in[4];
    const float* b1 = (const float*)d_in[5];
    const float* W2 = (const float*)d_in[6];
    const float* a_src2 = (const float*)d_in[7];
    const float* a_dst2 = (const float*)d_in[8];
    const float* b2 = (const float*)d_in[9];
    float* emb = (float*)d_out;

    const int* src = edge_index;
    const int* dst = edge_index + N_EDGES;

    // workspace carve
    char* w = (char*)d_ws;
    auto alloc = [&](size_t bytes) {
        char* p = w;
        w += (bytes + 255) & ~(size_t)255;
        return (void*)p;
    };
    const int NB = (N_NODES + 255) / 256;  // 391
    int* cnt = (int*)alloc(N_NODES * 4);
    int* row_ptr = (int*)alloc((N_NODES + 1) * 4);
    int* offs = (int*)alloc(N_NODES * 4);
    int* bs = (int*)alloc(NB * 4);
    int* col = (int*)alloc((size_t)N_EDGES * 4);
    __half* h1h = (__half*)alloc((size_t)N_NODES * C1 * 2);
    float* es1 = (float*)alloc(N_NODES * HEADS * 4);
    float* ed1 = (float*)alloc(N_NODES * HEADS * 4);
    __half* out1h = (__half*)alloc((size_t)N_NODES * C1 * 2);
    __half* h2h = (__half*)alloc((size_t)N_NODES * OUT_DIM * 2);
    float* es2 = (float*)alloc(N_NODES * 4);
    float* ed2 = (float*)alloc(N_NODES * 4);

    // CSR build
    hipMemsetAsync(cnt, 0, N_NODES * 4, stream);
    k_hist<<<(N_EDGES + 255) / 256, 256, 0, stream>>>(dst, cnt, N_EDGES);
    k_scan_local<<<NB, 256, 0, stream>>>(cnt, row_ptr, bs, N_NODES);
    k_scan_totals<<<1, 512, 0, stream>>>(bs, NB, row_ptr + N_NODES);
    k_scan_add<<<NB, 256, 0, stream>>>(row_ptr, offs, bs, N_NODES);
    k_scatter<<<(N_EDGES + 255) / 256, 256, 0, stream>>>(src, dst, offs, col, N_EDGES);

    // layer 1
    k_gemm1<<<(N_NODES + BM1 - 1) / BM1, 256, 0, stream>>>(x, W1, h1h, N_NODES);
    k_att1<<<(N_NODES + 3) / 4, 256, 0, stream>>>(h1h, a_src1, a_dst1, es1, ed1, N_NODES);
    k_aggr1<<<(N_NODES + 3) / 4, 256, 0, stream>>>(h1h, es1, ed1, row_ptr, col, b1, out1h, N_NODES);

    // layer 2
    k_gemm2<<<(N_NODES + 7) / 8, 256, 0, stream>>>(out1h, W2, h2h, a_src2, a_dst2, es2, ed2, N_NODES);
    k_aggr2<<<(N_NODES + 3) / 4, 256, 0, stream>>>(h2h, es2, ed2, row_ptr, col, b2, emb, N_NODES);
}

// Round 3
// 563.961 us; speedup vs baseline: 1.5205x; 1.3126x over previous
//
#include <hip/hip_runtime.h>
#include <hip/hip_bf16.h>
#include <hip/hip_fp16.h>

#define N_NODES 100000
#define N_EDGES 1600000
#define IN_DIM 128
#define C1 256      // HEADS*HID = 4*64
#define HID 64
#define HEADS 4
#define OUT_DIM 32
#define SLOPE 0.2f

typedef _Float16 f16x8 __attribute__((ext_vector_type(8)));
typedef float f32x4 __attribute__((ext_vector_type(4)));

__device__ __forceinline__ float leaky(float t) { return t > 0.f ? t : SLOPE * t; }

__device__ __forceinline__ float sel4(float a, float b, float c, float d, int k) {
    float lo = (k & 1) ? b : a;
    float hi = (k & 1) ? d : c;
    return (k & 2) ? hi : lo;
}

// ---------------- CSR build ----------------
__global__ void k_hist(const int* __restrict__ dst, int* __restrict__ cnt, int e) {
    int i = blockIdx.x * 256 + threadIdx.x;
    if (i < e) atomicAdd(&cnt[dst[i]], 1);
}

__global__ void k_scan_local(const int* __restrict__ cnt, int* __restrict__ row_ptr,
                             int* __restrict__ bs, int n) {
    __shared__ int sm[256];
    int tid = threadIdx.x;
    int gid = blockIdx.x * 256 + tid;
    int v = (gid < n) ? cnt[gid] : 0;
    sm[tid] = v;
    __syncthreads();
    for (int off = 1; off < 256; off <<= 1) {
        int u = (tid >= off) ? sm[tid - off] : 0;
        __syncthreads();
        sm[tid] += u;
        __syncthreads();
    }
    if (gid < n) row_ptr[gid] = sm[tid] - v;   // block-local exclusive
    if (tid == 255) bs[blockIdx.x] = sm[255];
}

__global__ void k_scan_totals(int* __restrict__ bs, int nb, int* __restrict__ row_ptr_last) {
    __shared__ int sm[512];
    int t = threadIdx.x;
    int v = (t < nb) ? bs[t] : 0;
    sm[t] = v;
    __syncthreads();
    for (int off = 1; off < 512; off <<= 1) {
        int u = (t >= off) ? sm[t - off] : 0;
        __syncthreads();
        sm[t] += u;
        __syncthreads();
    }
    if (t == nb - 1) *row_ptr_last = sm[t];       // total edge count
    if (t < nb) bs[t] = (t == 0) ? 0 : sm[t - 1]; // exclusive block offsets
}

__global__ void k_scan_add(int* __restrict__ row_ptr, int* __restrict__ offs,
                           const int* __restrict__ bs, int n) {
    int gid = blockIdx.x * 256 + threadIdx.x;
    if (gid < n) {
        int v = row_ptr[gid] + bs[blockIdx.x];
        row_ptr[gid] = v;
        offs[gid] = v;
    }
}

__global__ void k_scatter(const int* __restrict__ src, const int* __restrict__ dst,
                          int* __restrict__ offs, int* __restrict__ col, int e) {
    int i = blockIdx.x * 256 + threadIdx.x;
    if (i < e) {
        int p = atomicAdd(&offs[dst[i]], 1);
        col[p] = src[i];
    }
}

// ---------------- W1 -> fp16 MFMA fragment order ----------------
// frag element (kc, c, lane, v) = B[k][n], k = kc*32 + (lane>>4)*8 + v, n = c*16 + (lane&15)
__global__ void k_wfrag(const float* __restrict__ W, f16x8* __restrict__ out) {
    int t = blockIdx.x * 256 + threadIdx.x;
    if (t >= 4096) return;
    int kc = t >> 10, c = (t >> 6) & 15, lane = t & 63;
    int k0 = kc * 32 + ((lane >> 4) << 3), nn = c * 16 + (lane & 15);
    f16x8 r;
#pragma unroll
    for (int v = 0; v < 8; v++) r[v] = (_Float16)W[(k0 + v) * 256 + nn];
    out[t] = r;
}

// ---------------- GEMM1 (MFMA): h1 = x @ W1, (N x 128)@(128 x 256), fp16 out ----------------
// h1h layout: natural row-major [node][col], col = head*64 + hid
#define LDA 136   // halves (128 + 8 pad), 272B stride, 16B aligned
#define LDO 264   // halves (256 + 8 pad), 528B stride, 16B aligned
__launch_bounds__(256)
__global__ void k_gemm1(const float* __restrict__ x, const f16x8* __restrict__ Wfrag,
                        __half* __restrict__ h1h, int n) {
    __shared__ __align__(16) __half sm[64 * LDO];  // 33.8 KB (A overlays first 64*LDA)
    int tid = threadIdx.x, lane = tid & 63, w = tid >> 6;
    int row0 = blockIdx.x * 64;

    // B fragments: loaded once per block, held in registers
    f16x8 bf[4][4];
#pragma unroll
    for (int kc = 0; kc < 4; kc++)
#pragma unroll
        for (int cc = 0; cc < 4; cc++)
            bf[kc][cc] = Wfrag[(kc * 16 + w * 4 + cc) * 64 + lane];

    // stage A tile (64 rows x 128 k) as fp16 into LDS
    for (int i = tid; i < 64 * 32; i += 256) {
        int r = i >> 5, c4 = i & 31;
        float4 v = make_float4(0.f, 0.f, 0.f, 0.f);
        if (row0 + r < n) v = *(const float4*)(x + (size_t)(row0 + r) * 128 + c4 * 4);
        __half2 h0 = __halves2half2(__float2half(v.x), __float2half(v.y));
        __half2 h1 = __halves2half2(__float2half(v.z), __float2half(v.w));
        uint2 u;
        u.x = *(uint*)&h0;
        u.y = *(uint*)&h1;
        *(uint2*)(sm + r * LDA + c4 * 4) = u;
    }
    __syncthreads();

    f32x4 acc[4][4];
#pragma unroll
    for (int rf = 0; rf < 4; rf++)
#pragma unroll
        for (int cc = 0; cc < 4; cc++) acc[rf][cc] = (f32x4){0.f, 0.f, 0.f, 0.f};

#pragma unroll
    for (int kc = 0; kc < 4; kc++) {
        f16x8 af[4];
#pragma unroll
        for (int rf = 0; rf < 4; rf++) {
            int row = rf * 16 + (lane & 15);
            int koff = kc * 32 + ((lane >> 4) << 3);
            af[rf] = *(const f16x8*)(sm + row * LDA + koff);
        }
#pragma unroll
        for (int rf = 0; rf < 4; rf++)
#pragma unroll
            for (int cc = 0; cc < 4; cc++)
                acc[rf][cc] = __builtin_amdgcn_mfma_f32_16x16x32_f16(af[rf], bf[kc][cc],
                                                                     acc[rf][cc], 0, 0, 0);
    }
    __syncthreads();  // all waves done reading A before overlay write

    // epilogue: stage fp16 results row-major [64][LDO]
#pragma unroll
    for (int rf = 0; rf < 4; rf++)
#pragma unroll
        for (int cc = 0; cc < 4; cc++) {
            int colp = w * 64 + cc * 16 + (lane & 15);
            int rb = rf * 16 + ((lane >> 4) << 2);
#pragma unroll
            for (int j = 0; j < 4; j++) sm[(rb + j) * LDO + colp] = __float2half(acc[rf][cc][j]);
        }
    __syncthreads();

    // coalesced global store
    for (int i = tid; i < 64 * 32; i += 256) {
        int r = i >> 5, cb = i & 31;
        if (row0 + r < n) {
            uint4 u = *(const uint4*)(sm + r * LDO + cb * 8);
            *(uint4*)(h1h + (size_t)(row0 + r) * 256 + cb * 8) = u;
        }
    }
}

// ---------------- att logits layer1: one wave per node ----------------
__global__ void k_att1(const __half* __restrict__ h1h, const float* __restrict__ a_src,
                       const float* __restrict__ a_dst, float* __restrict__ es,
                       float* __restrict__ ed, int n) {
    int lane = threadIdx.x & 63;
    int node = blockIdx.x * 4 + (threadIdx.x >> 6);
    if (node >= n) return;
    uint2 raw = *reinterpret_cast<const uint2*>(h1h + (size_t)node * 256 + lane * 4);
    __half2 p01 = *reinterpret_cast<__half2*>(&raw.x);
    __half2 p23 = *reinterpret_cast<__half2*>(&raw.y);
    float v0 = __half2float(p01.x), v1 = __half2float(p01.y);
    float v2 = __half2float(p23.x), v3 = __half2float(p23.y);
    float4 as4 = *(const float4*)(a_src + lane * 4);
    float4 ad4 = *(const float4*)(a_dst + lane * 4);
    float ps = v0 * as4.x + v1 * as4.y + v2 * as4.z + v3 * as4.w;
    float pd = v0 * ad4.x + v1 * ad4.y + v2 * ad4.z + v3 * ad4.w;
#pragma unroll
    for (int off = 8; off; off >>= 1) {
        ps += __shfl_xor(ps, off);
        pd += __shfl_xor(pd, off);
    }
    if ((lane & 15) == 0) {
        es[node * 4 + (lane >> 4)] = ps;
        ed[node * 4 + (lane >> 4)] = pd;
    }
}

// ---------------- layer1 aggregation: one wave per node, single pass ----------------
// lane owns head k0 = lane>>4, channels (hid) = (lane&15)*4 .. +3 (cols 4*lane..4*lane+3)
__global__ void k_aggr1(const __half* __restrict__ h1h, const float* __restrict__ es,
                        const float* __restrict__ ed, const int* __restrict__ row_ptr,
                        const int* __restrict__ col, const float* __restrict__ b,
                        __half* __restrict__ out1h, int n) {
    int lane = threadIdx.x & 63;
    int node = blockIdx.x * 4 + (threadIdx.x >> 6);
    if (node >= n) return;
    int k0 = lane >> 4;
    float4 ed4 = ((const float4*)ed)[node];
    float4 es4 = ((const float4*)es)[node];
    float edk = sel4(ed4.x, ed4.y, ed4.z, ed4.w, k0);
    float esk = sel4(es4.x, es4.y, es4.z, es4.w, k0);
    // self contribution
    uint2 sraw = *reinterpret_cast<const uint2*>(h1h + (size_t)node * 256 + lane * 4);
    __half2 sp01 = *reinterpret_cast<__half2*>(&sraw.x);
    __half2 sp23 = *reinterpret_cast<__half2*>(&sraw.y);
    float tself = expf(leaky(esk + edk));
    float acc0 = tself * __half2float(sp01.x);
    float acc1 = tself * __half2float(sp01.y);
    float acc2 = tself * __half2float(sp23.x);
    float acc3 = tself * __half2float(sp23.y);
    float dl[4];
    dl[0] = (lane == 0) ? expf(leaky(es4.x + ed4.x)) : 0.f;
    dl[1] = (lane == 0) ? expf(leaky(es4.y + ed4.y)) : 0.f;
    dl[2] = (lane == 0) ? expf(leaky(es4.z + ed4.z)) : 0.f;
    dl[3] = (lane == 0) ? expf(leaky(es4.w + ed4.w)) : 0.f;
    int beg = row_ptr[node], end = row_ptr[node + 1];
    for (int base = beg; base < end; base += 64) {
        int nv = end - base;
        if (nv > 64) nv = 64;
        int j = base + lane;
        int s = 0;
        float exl[4] = {0.f, 0.f, 0.f, 0.f};
        if (j < end) {
            s = col[j];
            float4 e4 = ((const float4*)es)[s];
            exl[0] = expf(leaky(e4.x + ed4.x));
            exl[1] = expf(leaky(e4.y + ed4.y));
            exl[2] = expf(leaky(e4.z + ed4.z));
            exl[3] = expf(leaky(e4.w + ed4.w));
            dl[0] += exl[0];
            dl[1] += exl[1];
            dl[2] += exl[2];
            dl[3] += exl[3];
        }
        for (int j2 = 0; j2 < nv; j2++) {
            int sb = __shfl(s, j2);
            float b0 = __shfl(exl[0], j2);
            float b1 = __shfl(exl[1], j2);
            float b2 = __shfl(exl[2], j2);
            float b3 = __shfl(exl[3], j2);
            float e = sel4(b0, b1, b2, b3, k0);
            uint2 raw = *reinterpret_cast<const uint2*>(h1h + (size_t)sb * 256 + lane * 4);
            __half2 p01 = *reinterpret_cast<__half2*>(&raw.x);
            __half2 p23 = *reinterpret_cast<__half2*>(&raw.y);
            acc0 += e * __half2float(p01.x);
            acc1 += e * __half2float(p01.y);
            acc2 += e * __half2float(p23.x);
            acc3 += e * __half2float(p23.y);
        }
    }
#pragma unroll
    for (int off = 32; off; off >>= 1) {
#pragma unroll
        for (int k = 0; k < 4; k++) dl[k] += __shfl_xor(dl[k], off);
    }
    float dlk = sel4(dl[0], dl[1], dl[2], dl[3], k0) + 1e-16f;
    float4 bv = *(const float4*)(b + lane * 4);
    float o0 = acc0 / dlk + bv.x;
    float o1 = acc1 / dlk + bv.y;
    float o2 = acc2 / dlk + bv.z;
    float o3 = acc3 / dlk + bv.w;
    o0 = o0 > 0.f ? o0 : expm1f(o0);
    o1 = o1 > 0.f ? o1 : expm1f(o1);
    o2 = o2 > 0.f ? o2 : expm1f(o2);
    o3 = o3 > 0.f ? o3 : expm1f(o3);
    __half2 lo = __halves2half2(__float2half(o0), __float2half(o1));
    __half2 hi = __halves2half2(__float2half(o2), __float2half(o3));
    uint2 u;
    u.x = *(uint*)&lo;
    u.y = *(uint*)&hi;
    *(uint2*)(out1h + (size_t)node * 256 + lane * 4) = u;
}

// ---------------- GEMM2: h2 = out1 @ W2  (N x 256)@(256 x 32), fused e2, fp16 ----------------
__launch_bounds__(256)
__global__ void k_gemm2(const __half* __restrict__ A, const float* __restrict__ W,
                        __half* __restrict__ h2h, const float* __restrict__ a_src,
                        const float* __restrict__ a_dst, float* __restrict__ es,
                        float* __restrict__ ed, int n) {
    __shared__ float sW[C1 * OUT_DIM];  // 32 KB
    __shared__ float sA[8 * C1];        // 8 KB
    int tid = threadIdx.x;
    for (int i = tid; i < C1 * OUT_DIM; i += 256) sW[i] = W[i];
    int row0 = blockIdx.x * 8;
    for (int i = tid; i < 8 * C1; i += 256) {
        int r = i >> 8, k = i & 255;
        int gr = row0 + r;
        sA[i] = (gr < n) ? __half2float(A[(size_t)gr * C1 + k]) : 0.f;
    }
    __syncthreads();
    int col = tid & 31, r = tid >> 5;
    float acc = 0.f;
#pragma unroll 8
    for (int k = 0; k < C1; k++) acc += sA[r * C1 + k] * sW[k * OUT_DIM + col];
    float ps = acc * a_src[col], pd = acc * a_dst[col];
#pragma unroll
    for (int off = 16; off; off >>= 1) {
        ps += __shfl_xor(ps, off, 32);
        pd += __shfl_xor(pd, off, 32);
    }
    int gr = row0 + r;
    if (gr < n) {
        h2h[(size_t)gr * OUT_DIM + col] = __float2half(acc);
        if (col == 0) {
            es[gr] = ps;
            ed[gr] = pd;
        }
    }
}

// ---------------- layer2 aggregation: one wave per node, single pass ----------------
__global__ void k_aggr2(const __half* __restrict__ h2h, const float* __restrict__ es,
                        const float* __restrict__ ed, const int* __restrict__ row_ptr,
                        const int* __restrict__ col, const float* __restrict__ b,
                        float* __restrict__ emb, int n) {
    int lane = threadIdx.x & 63;
    int node = blockIdx.x * 4 + (threadIdx.x >> 6);
    if (node >= n) return;
    float edv = ed[node];
    float selft = expf(leaky(es[node] + edv));
    int c = lane & 31, half_ = lane >> 5;
    float acc = (lane < 32) ? selft * __half2float(h2h[(size_t)node * OUT_DIM + c]) : 0.f;
    float dl = (lane == 0) ? selft : 0.f;
    int beg = row_ptr[node], end = row_ptr[node + 1];
    for (int base = beg; base < end; base += 64) {
        int nv = end - base;
        if (nv > 64) nv = 64;
        int j = base + lane;
        int s = 0;
        float exl = 0.f;
        if (j < end) {
            s = col[j];
            exl = expf(leaky(es[s] + edv));
            dl += exl;
        }
        for (int j2 = 0; j2 < nv; j2 += 2) {
            int jj = j2 + half_;
            int sb = __shfl(s, jj);
            float eb = __shfl(exl, jj);
            if (jj < nv) acc += eb * __half2float(h2h[(size_t)sb * OUT_DIM + c]);
        }
    }
    acc += __shfl_xor(acc, 32);
#pragma unroll
    for (int off = 32; off; off >>= 1) dl += __shfl_xor(dl, off);
    if (lane < 32) emb[(size_t)node * OUT_DIM + c] = acc / (dl + 1e-16f) + b[c];
}

extern "C" void kernel_launch(void* const* d_in, const int* in_sizes, int n_in,
                              void* d_out, int out_size, void* d_ws, size_t ws_size,
                              hipStream_t stream) {
    const float* x = (const float*)d_in[0];
    const int* edge_index = (const int*)d_in[1];
    const float* W1 = (const float*)d_in[2];
    const float* a_src1 = (const float*)d_in[3];
    const float* a_dst1 = (const float*)d_in[4];
    const float* b1 = (const float*)d_in[5];
    const float* W2 = (const float*)d_in[6];
    const float* a_src2 = (const float*)d_in[7];
    const float* a_dst2 = (const float*)d_in[8];
    const float* b2 = (const float*)d_in[9];
    float* emb = (float*)d_out;

    const int* src = edge_index;
    const int* dst = edge_index + N_EDGES;

    // workspace carve
    char* w = (char*)d_ws;
    auto alloc = [&](size_t bytes) {
        char* p = w;
        w += (bytes + 255) & ~(size_t)255;
        return (void*)p;
    };
    const int NB = (N_NODES + 255) / 256;  // 391
    int* cnt = (int*)alloc(N_NODES * 4);
    int* row_ptr = (int*)alloc((N_NODES + 1) * 4);
    int* offs = (int*)alloc(N_NODES * 4);
    int* bs = (int*)alloc(NB * 4);
    int* col = (int*)alloc((size_t)N_EDGES * 4);
    __half* h1h = (__half*)alloc((size_t)N_NODES * C1 * 2);
    float* es1 = (float*)alloc(N_NODES * HEADS * 4);
    float* ed1 = (float*)alloc(N_NODES * HEADS * 4);
    __half* out1h = (__half*)alloc((size_t)N_NODES * C1 * 2);
    __half* h2h = (__half*)alloc((size_t)N_NODES * OUT_DIM * 2);
    float* es2 = (float*)alloc(N_NODES * 4);
    float* ed2 = (float*)alloc(N_NODES * 4);
    f16x8* W1fr = (f16x8*)alloc(4096 * 16);  // 64 KB fragment-ordered W1

    // CSR build
    hipMemsetAsync(cnt, 0, N_NODES * 4, stream);
    k_hist<<<(N_EDGES + 255) / 256, 256, 0, stream>>>(dst, cnt, N_EDGES);
    k_scan_local<<<NB, 256, 0, stream>>>(cnt, row_ptr, bs, N_NODES);
    k_scan_totals<<<1, 512, 0, stream>>>(bs, NB, row_ptr + N_NODES);
    k_scan_add<<<NB, 256, 0, stream>>>(row_ptr, offs, bs, N_NODES);
    k_scatter<<<(N_EDGES + 255) / 256, 256, 0, stream>>>(src, dst, offs, col, N_EDGES);

    // layer 1
    k_wfrag<<<16, 256, 0, stream>>>(W1, W1fr);
    k_gemm1<<<(N_NODES + 63) / 64, 256, 0, stream>>>(x, W1fr, h1h, N_NODES);
    k_att1<<<(N_NODES + 3) / 4, 256, 0, stream>>>(h1h, a_src1, a_dst1, es1, ed1, N_NODES);
    k_aggr1<<<(N_NODES + 3) / 4, 256, 0, stream>>>(h1h, es1, ed1, row_ptr, col, b1, out1h, N_NODES);

    // layer 2
    k_gemm2<<<(N_NODES + 7) / 8, 256, 0, stream>>>(out1h, W2, h2h, a_src2, a_dst2, es2, ed2, N_NODES);
    k_aggr2<<<(N_NODES + 3) / 4, 256, 0, stream>>>(h2h, es2, ed2, row_ptr, col, b2, emb, N_NODES);
}

// Round 4
// 444.906 us; speedup vs baseline: 1.9274x; 1.2676x over previous
//
#include <hip/hip_runtime.h>
#include <hip/hip_bf16.h>
#include <hip/hip_fp16.h>

#define N_NODES 100000
#define N_EDGES 1600000
#define IN_DIM 128
#define C1 256      // HEADS*HID = 4*64
#define HID 64
#define HEADS 4
#define OUT_DIM 32
#define SLOPE 0.2f

typedef _Float16 f16x8 __attribute__((ext_vector_type(8)));
typedef float f32x4 __attribute__((ext_vector_type(4)));

__device__ __forceinline__ float leaky(float t) { return t > 0.f ? t : SLOPE * t; }

__device__ __forceinline__ float sel4(float a, float b, float c, float d, int k) {
    float lo = (k & 1) ? b : a;
    float hi = (k & 1) ? d : c;
    return (k & 2) ? hi : lo;
}

// ---------------- CSR build ----------------
__global__ void k_hist(const int* __restrict__ dst, int* __restrict__ cnt, int e) {
    int i = blockIdx.x * 256 + threadIdx.x;
    if (i < e) atomicAdd(&cnt[dst[i]], 1);
}

__global__ void k_scan_local(const int* __restrict__ cnt, int* __restrict__ row_ptr,
                             int* __restrict__ bs, int n) {
    __shared__ int sm[256];
    int tid = threadIdx.x;
    int gid = blockIdx.x * 256 + tid;
    int v = (gid < n) ? cnt[gid] : 0;
    sm[tid] = v;
    __syncthreads();
    for (int off = 1; off < 256; off <<= 1) {
        int u = (tid >= off) ? sm[tid - off] : 0;
        __syncthreads();
        sm[tid] += u;
        __syncthreads();
    }
    if (gid < n) row_ptr[gid] = sm[tid] - v;   // block-local exclusive
    if (tid == 255) bs[blockIdx.x] = sm[255];
}

__global__ void k_scan_totals(int* __restrict__ bs, int nb, int* __restrict__ row_ptr_last) {
    __shared__ int sm[512];
    int t = threadIdx.x;
    int v = (t < nb) ? bs[t] : 0;
    sm[t] = v;
    __syncthreads();
    for (int off = 1; off < 512; off <<= 1) {
        int u = (t >= off) ? sm[t - off] : 0;
        __syncthreads();
        sm[t] += u;
        __syncthreads();
    }
    if (t == nb - 1) *row_ptr_last = sm[t];       // total edge count
    if (t < nb) bs[t] = (t == 0) ? 0 : sm[t - 1]; // exclusive block offsets
}

__global__ void k_scan_add(int* __restrict__ row_ptr, int* __restrict__ offs,
                           const int* __restrict__ bs, int n) {
    int gid = blockIdx.x * 256 + threadIdx.x;
    if (gid < n) {
        int v = row_ptr[gid] + bs[blockIdx.x];
        row_ptr[gid] = v;
        offs[gid] = v;
    }
}

__global__ void k_scatter(const int* __restrict__ src, const int* __restrict__ dst,
                          int* __restrict__ offs, int* __restrict__ col, int e) {
    int i = blockIdx.x * 256 + threadIdx.x;
    if (i < e) {
        int p = atomicAdd(&offs[dst[i]], 1);
        col[p] = src[i];
    }
}

// ---------------- W1 -> fp16 MFMA fragment order ----------------
// frag element (kc, c, lane, v) = B[k][n], k = kc*32 + (lane>>4)*8 + v, n = c*16 + (lane&15)
__global__ void k_wfrag(const float* __restrict__ W, f16x8* __restrict__ out) {
    int t = blockIdx.x * 256 + threadIdx.x;
    if (t >= 4096) return;
    int kc = t >> 10, c = (t >> 6) & 15, lane = t & 63;
    int k0 = kc * 32 + ((lane >> 4) << 3), nn = c * 16 + (lane & 15);
    f16x8 r;
#pragma unroll
    for (int v = 0; v < 8; v++) r[v] = (_Float16)W[(k0 + v) * 256 + nn];
    out[t] = r;
}

// W2 (256x32) -> fragments: kc 0..7, cc 0..1
__global__ void k_wfrag2(const float* __restrict__ W, f16x8* __restrict__ out) {
    int t = blockIdx.x * 256 + threadIdx.x;
    if (t >= 1024) return;
    int kc = t >> 7, c = (t >> 6) & 1, lane = t & 63;
    int k0 = kc * 32 + ((lane >> 4) << 3), nn = c * 16 + (lane & 15);
    f16x8 r;
#pragma unroll
    for (int v = 0; v < 8; v++) r[v] = (_Float16)W[(k0 + v) * 32 + nn];
    out[t] = r;
}

// ---------------- GEMM1 (MFMA): h1 = x @ W1, (N x 128)@(128 x 256), fp16 out ----------------
#define LDA 136   // halves (128 + 8 pad), 272B stride, 16B aligned
#define LDO 264   // halves (256 + 8 pad), 528B stride, 16B aligned
__launch_bounds__(256)
__global__ void k_gemm1(const float* __restrict__ x, const f16x8* __restrict__ Wfrag,
                        __half* __restrict__ h1h, int n) {
    __shared__ __align__(16) __half sm[64 * LDO];  // 33.8 KB (A overlays first 64*LDA)
    int tid = threadIdx.x, lane = tid & 63, w = tid >> 6;
    int row0 = blockIdx.x * 64;

    f16x8 bf[4][4];
#pragma unroll
    for (int kc = 0; kc < 4; kc++)
#pragma unroll
        for (int cc = 0; cc < 4; cc++)
            bf[kc][cc] = Wfrag[(kc * 16 + w * 4 + cc) * 64 + lane];

    for (int i = tid; i < 64 * 32; i += 256) {
        int r = i >> 5, c4 = i & 31;
        float4 v = make_float4(0.f, 0.f, 0.f, 0.f);
        if (row0 + r < n) v = *(const float4*)(x + (size_t)(row0 + r) * 128 + c4 * 4);
        __half2 h0 = __halves2half2(__float2half(v.x), __float2half(v.y));
        __half2 h1 = __halves2half2(__float2half(v.z), __float2half(v.w));
        uint2 u;
        u.x = *(uint*)&h0;
        u.y = *(uint*)&h1;
        *(uint2*)(sm + r * LDA + c4 * 4) = u;
    }
    __syncthreads();

    f32x4 acc[4][4];
#pragma unroll
    for (int rf = 0; rf < 4; rf++)
#pragma unroll
        for (int cc = 0; cc < 4; cc++) acc[rf][cc] = (f32x4){0.f, 0.f, 0.f, 0.f};

#pragma unroll
    for (int kc = 0; kc < 4; kc++) {
        f16x8 af[4];
#pragma unroll
        for (int rf = 0; rf < 4; rf++) {
            int row = rf * 16 + (lane & 15);
            int koff = kc * 32 + ((lane >> 4) << 3);
            af[rf] = *(const f16x8*)(sm + row * LDA + koff);
        }
#pragma unroll
        for (int rf = 0; rf < 4; rf++)
#pragma unroll
            for (int cc = 0; cc < 4; cc++)
                acc[rf][cc] = __builtin_amdgcn_mfma_f32_16x16x32_f16(af[rf], bf[kc][cc],
                                                                     acc[rf][cc], 0, 0, 0);
    }
    __syncthreads();

#pragma unroll
    for (int rf = 0; rf < 4; rf++)
#pragma unroll
        for (int cc = 0; cc < 4; cc++) {
            int colp = w * 64 + cc * 16 + (lane & 15);
            int rb = rf * 16 + ((lane >> 4) << 2);
#pragma unroll
            for (int j = 0; j < 4; j++) sm[(rb + j) * LDO + colp] = __float2half(acc[rf][cc][j]);
        }
    __syncthreads();

    for (int i = tid; i < 64 * 32; i += 256) {
        int r = i >> 5, cb = i & 31;
        if (row0 + r < n) {
            uint4 u = *(const uint4*)(sm + r * LDO + cb * 8);
            *(uint4*)(h1h + (size_t)(row0 + r) * 256 + cb * 8) = u;
        }
    }
}

// ---------------- att logits layer1: one wave per node ----------------
__global__ void k_att1(const __half* __restrict__ h1h, const float* __restrict__ a_src,
                       const float* __restrict__ a_dst, float* __restrict__ es,
                       float* __restrict__ ed, int n) {
    int lane = threadIdx.x & 63;
    int node = blockIdx.x * 4 + (threadIdx.x >> 6);
    if (node >= n) return;
    uint2 raw = *reinterpret_cast<const uint2*>(h1h + (size_t)node * 256 + lane * 4);
    __half2 p01 = *reinterpret_cast<__half2*>(&raw.x);
    __half2 p23 = *reinterpret_cast<__half2*>(&raw.y);
    float v0 = __half2float(p01.x), v1 = __half2float(p01.y);
    float v2 = __half2float(p23.x), v3 = __half2float(p23.y);
    float4 as4 = *(const float4*)(a_src + lane * 4);
    float4 ad4 = *(const float4*)(a_dst + lane * 4);
    float ps = v0 * as4.x + v1 * as4.y + v2 * as4.z + v3 * as4.w;
    float pd = v0 * ad4.x + v1 * ad4.y + v2 * ad4.z + v3 * ad4.w;
#pragma unroll
    for (int off = 8; off; off >>= 1) {
        ps += __shfl_xor(ps, off);
        pd += __shfl_xor(pd, off);
    }
    if ((lane & 15) == 0) {
        es[node * 4 + (lane >> 4)] = ps;
        ed[node * 4 + (lane >> 4)] = pd;
    }
}

// ---------------- layer1 aggregation: one wave per node, single pass ----------------
// lane owns cols 4*lane..4*lane+3 (head k0 = lane>>4); LDS-staged edge (src, alpha[4])
__global__ void k_aggr1(const __half* __restrict__ h1h, const float* __restrict__ es,
                        const float* __restrict__ ed, const int* __restrict__ row_ptr,
                        const int* __restrict__ col, const float* __restrict__ b,
                        __half* __restrict__ out1h, int n) {
    __shared__ int s_idx[4][64];
    __shared__ __align__(16) float s_al[4][256];
    int tid = threadIdx.x, lane = tid & 63, w = tid >> 6;
    int node = blockIdx.x * 4 + w;
    if (node >= n) return;
    int k0 = lane >> 4;
    float4 ed4 = ((const float4*)ed)[node];
    float4 es4 = ((const float4*)es)[node];
    float edk = sel4(ed4.x, ed4.y, ed4.z, ed4.w, k0);
    float esk = sel4(es4.x, es4.y, es4.z, es4.w, k0);
    uint2 sraw = *reinterpret_cast<const uint2*>(h1h + (size_t)node * 256 + lane * 4);
    __half2 sp01 = *reinterpret_cast<__half2*>(&sraw.x);
    __half2 sp23 = *reinterpret_cast<__half2*>(&sraw.y);
    float tself = __expf(leaky(esk + edk));
    float acc0 = tself * __half2float(sp01.x);
    float acc1 = tself * __half2float(sp01.y);
    float acc2 = tself * __half2float(sp23.x);
    float acc3 = tself * __half2float(sp23.y);
    float dl[4];
    dl[0] = (lane == 0) ? __expf(leaky(es4.x + ed4.x)) : 0.f;
    dl[1] = (lane == 0) ? __expf(leaky(es4.y + ed4.y)) : 0.f;
    dl[2] = (lane == 0) ? __expf(leaky(es4.z + ed4.z)) : 0.f;
    dl[3] = (lane == 0) ? __expf(leaky(es4.w + ed4.w)) : 0.f;
    int beg = row_ptr[node], end = row_ptr[node + 1];
    for (int base = beg; base < end; base += 64) {
        int nv = end - base;
        if (nv > 64) nv = 64;
        int j = base + lane;
        int s = 0;
        float e0 = 0.f, e1 = 0.f, e2 = 0.f, e3 = 0.f;
        if (j < end) {
            s = col[j];
            float4 e4 = ((const float4*)es)[s];
            e0 = __expf(leaky(e4.x + ed4.x));
            e1 = __expf(leaky(e4.y + ed4.y));
            e2 = __expf(leaky(e4.z + ed4.z));
            e3 = __expf(leaky(e4.w + ed4.w));
            dl[0] += e0;
            dl[1] += e1;
            dl[2] += e2;
            dl[3] += e3;
        }
        s_idx[w][lane] = s;
        *(float4*)&s_al[w][lane * 4] = make_float4(e0, e1, e2, e3);
        for (int j2 = 0; j2 < nv; j2++) {
            int sb = s_idx[w][j2];
            float e = s_al[w][j2 * 4 + k0];
            uint2 raw = *reinterpret_cast<const uint2*>(h1h + (size_t)sb * 256 + lane * 4);
            __half2 p01 = *reinterpret_cast<__half2*>(&raw.x);
            __half2 p23 = *reinterpret_cast<__half2*>(&raw.y);
            acc0 += e * __half2float(p01.x);
            acc1 += e * __half2float(p01.y);
            acc2 += e * __half2float(p23.x);
            acc3 += e * __half2float(p23.y);
        }
    }
#pragma unroll
    for (int off = 32; off; off >>= 1) {
#pragma unroll
        for (int k = 0; k < 4; k++) dl[k] += __shfl_xor(dl[k], off);
    }
    float dlk = sel4(dl[0], dl[1], dl[2], dl[3], k0) + 1e-16f;
    float4 bv = *(const float4*)(b + lane * 4);
    float o0 = acc0 / dlk + bv.x;
    float o1 = acc1 / dlk + bv.y;
    float o2 = acc2 / dlk + bv.z;
    float o3 = acc3 / dlk + bv.w;
    o0 = o0 > 0.f ? o0 : __expf(o0) - 1.f;
    o1 = o1 > 0.f ? o1 : __expf(o1) - 1.f;
    o2 = o2 > 0.f ? o2 : __expf(o2) - 1.f;
    o3 = o3 > 0.f ? o3 : __expf(o3) - 1.f;
    __half2 lo = __halves2half2(__float2half(o0), __float2half(o1));
    __half2 hi = __halves2half2(__float2half(o2), __float2half(o3));
    uint2 u;
    u.x = *(uint*)&lo;
    u.y = *(uint*)&hi;
    *(uint2*)(out1h + (size_t)node * 256 + lane * 4) = u;
}

// ---------------- GEMM2 (MFMA): h2 = out1 @ W2, (N x 256)@(256 x 32), fp16 out ----------------
#define LDA2 264
__launch_bounds__(256)
__global__ void k_gemm2(const __half* __restrict__ A, const f16x8* __restrict__ Wfrag,
                        __half* __restrict__ h2h, int n) {
    __shared__ __align__(16) __half sm[64 * LDA2];  // 33.8 KB
    int tid = threadIdx.x, lane = tid & 63, w = tid >> 6;
    int row0 = blockIdx.x * 64;

    f16x8 bf[8][2];
#pragma unroll
    for (int kc = 0; kc < 8; kc++)
#pragma unroll
        for (int cc = 0; cc < 2; cc++)
            bf[kc][cc] = Wfrag[(kc * 2 + cc) * 64 + lane];

    for (int i = tid; i < 64 * 32; i += 256) {
        int r = i >> 5, cb = i & 31;
        uint4 u = make_uint4(0, 0, 0, 0);
        if (row0 + r < n) u = *(const uint4*)(A + (size_t)(row0 + r) * 256 + cb * 8);
        *(uint4*)(sm + r * LDA2 + cb * 8) = u;
    }
    __syncthreads();

    f32x4 acc[2];
    acc[0] = (f32x4){0.f, 0.f, 0.f, 0.f};
    acc[1] = (f32x4){0.f, 0.f, 0.f, 0.f};
    int arow = w * 16 + (lane & 15);
#pragma unroll
    for (int kc = 0; kc < 8; kc++) {
        f16x8 af = *(const f16x8*)(sm + arow * LDA2 + kc * 32 + ((lane >> 4) << 3));
#pragma unroll
        for (int cc = 0; cc < 2; cc++)
            acc[cc] = __builtin_amdgcn_mfma_f32_16x16x32_f16(af, bf[kc][cc], acc[cc], 0, 0, 0);
    }
    int gr0 = row0 + w * 16 + ((lane >> 4) << 2);
#pragma unroll
    for (int cc = 0; cc < 2; cc++) {
        int colp = cc * 16 + (lane & 15);
#pragma unroll
        for (int j = 0; j < 4; j++) {
            int gr = gr0 + j;
            if (gr < n) h2h[(size_t)gr * 32 + colp] = __float2half(acc[cc][j]);
        }
    }
}

// ---------------- att logits layer2: 16 lanes per node ----------------
__global__ void k_att2(const __half* __restrict__ h2h, const float* __restrict__ a_src,
                       const float* __restrict__ a_dst, float* __restrict__ es,
                       float* __restrict__ ed, int n) {
    int tid = threadIdx.x, lane = tid & 63;
    int node = blockIdx.x * 16 + (tid >> 6) * 4 + (lane >> 4);
    if (node >= n) return;
    int cpair = lane & 15;
    uint raw = ((const uint*)h2h)[(size_t)node * 16 + cpair];
    __half2 p = *reinterpret_cast<__half2*>(&raw);
    float v0 = __half2float(p.x), v1 = __half2float(p.y);
    float2 as2 = ((const float2*)a_src)[cpair];
    float2 ad2 = ((const float2*)a_dst)[cpair];
    float ps = v0 * as2.x + v1 * as2.y;
    float pd = v0 * ad2.x + v1 * ad2.y;
#pragma unroll
    for (int off = 8; off; off >>= 1) {
        ps += __shfl_xor(ps, off);
        pd += __shfl_xor(pd, off);
    }
    if (cpair == 0) {
        es[node] = ps;
        ed[node] = pd;
    }
}

// ---------------- layer2 aggregation: 16-lane groups, 4 edges/iter ----------------
__global__ void k_aggr2(const __half* __restrict__ h2h, const float* __restrict__ es,
                        const float* __restrict__ ed, const int* __restrict__ row_ptr,
                        const int* __restrict__ col, const float* __restrict__ b,
                        float* __restrict__ emb, int n) {
    __shared__ int s_idx[4][64];
    __shared__ float s_a[4][64];
    int tid = threadIdx.x, lane = tid & 63, w = tid >> 6;
    int node = blockIdx.x * 4 + w;
    if (node >= n) return;
    const uint* h2u = (const uint*)h2h;
    float edv = ed[node];
    float selft = __expf(leaky(es[node] + edv));
    int q = lane >> 4, cpair = lane & 15;
    uint sraw = h2u[(size_t)node * 16 + cpair];
    __half2 sh = *reinterpret_cast<__half2*>(&sraw);
    float acc0 = (q == 0) ? selft * __half2float(sh.x) : 0.f;
    float acc1 = (q == 0) ? selft * __half2float(sh.y) : 0.f;
    float dl = (lane == 0) ? selft : 0.f;
    int beg = row_ptr[node], end = row_ptr[node + 1];
    for (int base = beg; base < end; base += 64) {
        int nv = end - base;
        if (nv > 64) nv = 64;
        int j = base + lane;
        int s = 0;
        float exl = 0.f;
        if (j < end) {
            s = col[j];
            exl = __expf(leaky(es[s] + edv));
            dl += exl;
        }
        s_idx[w][lane] = s;
        s_a[w][lane] = exl;
        for (int j2 = 0; j2 < nv; j2 += 4) {
            int jj = j2 + q;
            int sb = s_idx[w][jj];
            float a = s_a[w][jj];
            if (jj < nv) {
                uint raw = h2u[(size_t)sb * 16 + cpair];
                __half2 p = *reinterpret_cast<__half2*>(&raw);
                acc0 += a * __half2float(p.x);
                acc1 += a * __half2float(p.y);
            }
        }
    }
    acc0 += __shfl_xor(acc0, 16);
    acc0 += __shfl_xor(acc0, 32);
    acc1 += __shfl_xor(acc1, 16);
    acc1 += __shfl_xor(acc1, 32);
#pragma unroll
    for (int off = 32; off; off >>= 1) dl += __shfl_xor(dl, off);
    if (lane < 16) {
        float inv = 1.f / (dl + 1e-16f);
        float2 bv = ((const float2*)b)[cpair];
        float2 o;
        o.x = acc0 * inv + bv.x;
        o.y = acc1 * inv + bv.y;
        *(float2*)(emb + (size_t)node * 32 + cpair * 2) = o;
    }
}

extern "C" void kernel_launch(void* const* d_in, const int* in_sizes, int n_in,
                              void* d_out, int out_size, void* d_ws, size_t ws_size,
                              hipStream_t stream) {
    const float* x = (const float*)d_in[0];
    const int* edge_index = (const int*)d_in[1];
    const float* W1 = (const float*)d_in[2];
    const float* a_src1 = (const float*)d_in[3];
    const float* a_dst1 = (const float*)d_in[4];
    const float* b1 = (const float*)d_in[5];
    const float* W2 = (const float*)d_in[6];
    const float* a_src2 = (const float*)d_in[7];
    const float* a_dst2 = (const float*)d_in[8];
    const float* b2 = (const float*)d_in[9];
    float* emb = (float*)d_out;

    const int* src = edge_index;
    const int* dst = edge_index + N_EDGES;

    char* w = (char*)d_ws;
    auto alloc = [&](size_t bytes) {
        char* p = w;
        w += (bytes + 255) & ~(size_t)255;
        return (void*)p;
    };
    const int NB = (N_NODES + 255) / 256;  // 391
    int* cnt = (int*)alloc(N_NODES * 4);
    int* row_ptr = (int*)alloc((N_NODES + 1) * 4);
    int* offs = (int*)alloc(N_NODES * 4);
    int* bs = (int*)alloc(NB * 4);
    int* col = (int*)alloc((size_t)N_EDGES * 4);
    __half* h1h = (__half*)alloc((size_t)N_NODES * C1 * 2);
    float* es1 = (float*)alloc(N_NODES * HEADS * 4);
    float* ed1 = (float*)alloc(N_NODES * HEADS * 4);
    __half* out1h = (__half*)alloc((size_t)N_NODES * C1 * 2);
    __half* h2h = (__half*)alloc((size_t)N_NODES * OUT_DIM * 2);
    float* es2 = (float*)alloc(N_NODES * 4);
    float* ed2 = (float*)alloc(N_NODES * 4);
    f16x8* W1fr = (f16x8*)alloc(4096 * 16);  // 64 KB
    f16x8* W2fr = (f16x8*)alloc(1024 * 16);  // 16 KB

    // CSR build
    hipMemsetAsync(cnt, 0, N_NODES * 4, stream);
    k_hist<<<(N_EDGES + 255) / 256, 256, 0, stream>>>(dst, cnt, N_EDGES);
    k_scan_local<<<NB, 256, 0, stream>>>(cnt, row_ptr, bs, N_NODES);
    k_scan_totals<<<1, 512, 0, stream>>>(bs, NB, row_ptr + N_NODES);
    k_scan_add<<<NB, 256, 0, stream>>>(row_ptr, offs, bs, N_NODES);
    k_scatter<<<(N_EDGES + 255) / 256, 256, 0, stream>>>(src, dst, offs, col, N_EDGES);

    // layer 1
    k_wfrag<<<16, 256, 0, stream>>>(W1, W1fr);
    k_gemm1<<<(N_NODES + 63) / 64, 256, 0, stream>>>(x, W1fr, h1h, N_NODES);
    k_att1<<<(N_NODES + 3) / 4, 256, 0, stream>>>(h1h, a_src1, a_dst1, es1, ed1, N_NODES);
    k_aggr1<<<(N_NODES + 3) / 4, 256, 0, stream>>>(h1h, es1, ed1, row_ptr, col, b1, out1h, N_NODES);

    // layer 2
    k_wfrag2<<<4, 256, 0, stream>>>(W2, W2fr);
    k_gemm2<<<(N_NODES + 63) / 64, 256, 0, stream>>>(out1h, W2fr, h2h, N_NODES);
    k_att2<<<(N_NODES + 15) / 16, 256, 0, stream>>>(h2h, a_src2, a_dst2, es2, ed2, N_NODES);
    k_aggr2<<<(N_NODES + 3) / 4, 256, 0, stream>>>(h2h, es2, ed2, row_ptr, col, b2, emb, N_NODES);
}